// Round 3
// baseline (405.188 us; speedup 1.0000x reference)
//
#include <hip/hip_runtime.h>
#include <math.h>

// Problem constants
#define NB   8
#define NPIX 4096          // H*W
#define MROW 32768         // B*H*W
#define CV_  256
#define TT   77
#define CT_  512
#define NH_  8
#define DH_  32
#define BT_  616           // B*T

typedef __bf16 bf16x8 __attribute__((ext_vector_type(8)));
typedef float  f32x4  __attribute__((ext_vector_type(4)));

__device__ __forceinline__ float bf2f(unsigned short u) {
  return __uint_as_float(((unsigned)u) << 16);
}
__device__ __forceinline__ unsigned short f2b(float f) {
  unsigned u = __float_as_uint(f);
  return (unsigned short)((u + 0x7FFFu + ((u >> 16) & 1u)) >> 16);
}
__device__ __forceinline__ unsigned pack2(float lo, float hi) {
  return ((unsigned)f2b(hi) << 16) | (unsigned)f2b(lo);
}

// ------------- convert+transpose: dst_bf16[c*R + r] = src_f32[r*C + c] ----
__global__ __launch_bounds__(256) void convT_k(
    const float* __restrict__ src, unsigned short* __restrict__ dst,
    int R, int C) {
  int idx = blockIdx.x * 256 + threadIdx.x;
  if (idx >= R * C) return;
  int r = idx / C, c = idx - r * C;
  dst[(size_t)c * R + r] = f2b(src[idx]);
}

// ---------------- LayerNorm over last dim (256); one wave per row --------
// flags: bit0 = src fp32 (else bf16), bit1 = dst fp32 (else bf16)
__global__ __launch_bounds__(256) void ln_kernel(
    const void* __restrict__ src, const float* __restrict__ g,
    const float* __restrict__ b, void* __restrict__ dst, int rows, int flags) {
  int wave = threadIdx.x >> 6, lane = threadIdx.x & 63;
  int row = blockIdx.x * 4 + wave;
  if (row >= rows) return;
  size_t base = (size_t)row * 256 + lane * 4;
  float v0, v1, v2, v3;
  if (flags & 1) {
    float4 f = *reinterpret_cast<const float4*>((const float*)src + base);
    v0 = f.x; v1 = f.y; v2 = f.z; v3 = f.w;
  } else {
    ushort4 u = *reinterpret_cast<const ushort4*>((const unsigned short*)src + base);
    v0 = bf2f(u.x); v1 = bf2f(u.y); v2 = bf2f(u.z); v3 = bf2f(u.w);
  }
  float s = v0 + v1 + v2 + v3;
  float q = v0 * v0 + v1 * v1 + v2 * v2 + v3 * v3;
#pragma unroll
  for (int off = 1; off < 64; off <<= 1) {
    s += __shfl_xor(s, off);
    q += __shfl_xor(q, off);
  }
  float mean = s * (1.0f / 256.0f);
  float var  = q * (1.0f / 256.0f) - mean * mean;
  float rstd = rsqrtf(var + 1e-5f);
  float4 gv = *reinterpret_cast<const float4*>(g + lane * 4);
  float4 bv = *reinterpret_cast<const float4*>(b + lane * 4);
  float o0 = (v0 - mean) * rstd * gv.x + bv.x;
  float o1 = (v1 - mean) * rstd * gv.y + bv.y;
  float o2 = (v2 - mean) * rstd * gv.z + bv.z;
  float o3 = (v3 - mean) * rstd * gv.w + bv.w;
  if (flags & 2) {
    *reinterpret_cast<float4*>((float*)dst + base) = make_float4(o0, o1, o2, o3);
  } else {
    ushort4 o;
    o.x = f2b(o0); o.y = f2b(o1); o.z = f2b(o2); o.w = f2b(o3);
    *reinterpret_cast<ushort4*>((unsigned short*)dst + base) = o;
  }
}

// ---------------- MFMA GEMM: C[M,N] = A[M,K] @ Bt[N,K]^T -----------------
// 64x64 tile, 4 waves (each 32x32 via 2x2 of 16x16x32_bf16), fp32 accum.
// flags: bit0 out fp32 (else bf16), bit1 exact-GELU, bit2 A fp32 (else bf16),
//        bit3 resid fp32 (else bf16)
// resid may alias out elementwise (same thread reads before writing).
__global__ __launch_bounds__(256) void gemm_bt(
    const void* __restrict__ A, const unsigned short* __restrict__ Bt,
    const float* __restrict__ bias, const void* resid,
    const float* __restrict__ alpha_ptr, void* out,
    int M, int N, int K, int flags) {
  __shared__ unsigned short lA[64 * 40];   // row stride 40 elems (80B, 16B-aligned)
  __shared__ unsigned short lB[64 * 40];
  int tid  = threadIdx.x;
  int bm   = blockIdx.x * 64, bn = blockIdx.y * 64;
  int srow = tid >> 2, sc8 = (tid & 3) * 8;
  int lane = tid & 63, wave = tid >> 6;
  int wm = (wave & 1) * 32, wn = (wave >> 1) * 32;
  int l15 = lane & 15, quad = lane >> 4;
  f32x4 acc[2][2] = {};
  int gm = bm + srow;
  int gn = bn + srow;
  const bool aok = (gm < M);
  for (int k0 = 0; k0 < K; k0 += 32) {
    uint4 apk = make_uint4(0, 0, 0, 0);
    if (aok) {
      if (flags & 4) {
        const float* Af = (const float*)A + (size_t)gm * K + k0 + sc8;
        float4 f0 = *reinterpret_cast<const float4*>(Af);
        float4 f1 = *reinterpret_cast<const float4*>(Af + 4);
        apk.x = pack2(f0.x, f0.y); apk.y = pack2(f0.z, f0.w);
        apk.z = pack2(f1.x, f1.y); apk.w = pack2(f1.z, f1.w);
      } else {
        apk = *reinterpret_cast<const uint4*>(
            (const unsigned short*)A + (size_t)gm * K + k0 + sc8);
      }
    }
    uint4 bpk = *reinterpret_cast<const uint4*>(Bt + (size_t)gn * K + k0 + sc8);
    *reinterpret_cast<uint4*>(&lA[srow * 40 + sc8]) = apk;
    *reinterpret_cast<uint4*>(&lB[srow * 40 + sc8]) = bpk;
    __syncthreads();
    bf16x8 a0 = *reinterpret_cast<const bf16x8*>(&lA[(wm + l15) * 40 + quad * 8]);
    bf16x8 a1 = *reinterpret_cast<const bf16x8*>(&lA[(wm + 16 + l15) * 40 + quad * 8]);
    bf16x8 b0 = *reinterpret_cast<const bf16x8*>(&lB[(wn + l15) * 40 + quad * 8]);
    bf16x8 b1 = *reinterpret_cast<const bf16x8*>(&lB[(wn + 16 + l15) * 40 + quad * 8]);
    acc[0][0] = __builtin_amdgcn_mfma_f32_16x16x32_bf16(a0, b0, acc[0][0], 0, 0, 0);
    acc[0][1] = __builtin_amdgcn_mfma_f32_16x16x32_bf16(a0, b1, acc[0][1], 0, 0, 0);
    acc[1][0] = __builtin_amdgcn_mfma_f32_16x16x32_bf16(a1, b0, acc[1][0], 0, 0, 0);
    acc[1][1] = __builtin_amdgcn_mfma_f32_16x16x32_bf16(a1, b1, acc[1][1], 0, 0, 0);
    __syncthreads();
  }
  float alpha = alpha_ptr ? *alpha_ptr : 1.0f;
#pragma unroll
  for (int mt = 0; mt < 2; ++mt) {
#pragma unroll
    for (int nt = 0; nt < 2; ++nt) {
      int gcol = bn + wn + nt * 16 + l15;
      float bsf = bias ? bias[gcol] : 0.0f;
#pragma unroll
      for (int r = 0; r < 4; ++r) {
        int grow = bm + wm + mt * 16 + quad * 4 + r;
        if (grow >= M) continue;
        float v = acc[mt][nt][r] + bsf;
        if (flags & 2) v = 0.5f * v * (1.0f + erff(v * 0.70710678118654752f));
        size_t oi = (size_t)grow * N + gcol;
        if (resid) {
          float rv = (flags & 8) ? ((const float*)resid)[oi]
                                 : bf2f(((const unsigned short*)resid)[oi]);
          v = rv + alpha * v;
        }
        if (flags & 1) ((float*)out)[oi] = v;
        else           ((unsigned short*)out)[oi] = f2b(v);
      }
    }
  }
}

// ---------------- k l2norm (per 32-dh group, in place) + pad mask --------
__global__ __launch_bounds__(256) void kv_post(
    const float* __restrict__ text, float* __restrict__ k,
    float* __restrict__ pad) {
  int bt = blockIdx.x;            // 0..615  (b*77 + t)
  int tid = threadIdx.x;
  __shared__ float red[4];
  const float* tr = text + (size_t)bt * CT_;
  float s = fabsf(tr[tid]) + fabsf(tr[tid + 256]);
#pragma unroll
  for (int off = 1; off < 64; off <<= 1) s += __shfl_xor(s, off);
  if ((tid & 63) == 0) red[tid >> 6] = s;
  __syncthreads();
  if (tid == 0) {
    float tot = red[0] + red[1] + red[2] + red[3];
    pad[bt] = (tot <= 1e-6f) ? 1.0f : 0.0f;
  }
  // l2-normalize k over each head's 32 dims (channels = h*32 + d)
  float v = k[(size_t)bt * CV_ + tid];
  float ss = v * v;
#pragma unroll
  for (int off = 1; off < 32; off <<= 1) ss += __shfl_xor(ss, off);
  float n = sqrtf(ss);
  k[(size_t)bt * CV_ + tid] = v / fmaxf(n, 1e-6f);
}

// ---------------- attention: top-5 masked cosine attention ---------------
// grid (16, NH, B), 256 thr; thread -> query n = bx*256+tid of head h, batch b
// qa: in = q (bf16), out = aligned, IN PLACE (each thread owns its 32-d slice)
__global__ __launch_bounds__(256) void attn_kernel(
    unsigned short* qa, const float* __restrict__ k,
    const unsigned short* __restrict__ v, const float* __restrict__ pad,
    const float* __restrict__ ls_ptr) {
  __shared__ float ks[TT * DH_];
  __shared__ float vs[TT * DH_];
  __shared__ float ps[TT];
  __shared__ int allpad_s;
  int tid = threadIdx.x;
  int h = blockIdx.y, b = blockIdx.z;
  size_t kvbase = (size_t)b * TT * CV_ + h * DH_;
  for (int idx = tid; idx < TT * DH_; idx += 256) {
    int t = idx >> 5, d = idx & 31;
    ks[idx] = k[kvbase + (size_t)t * CV_ + d];
    vs[idx] = bf2f(v[kvbase + (size_t)t * CV_ + d]);
  }
  if (tid < TT) ps[tid] = pad[b * TT + tid];
  if (tid == 0) allpad_s = 1;
  __syncthreads();
  if (tid < TT && ps[tid] == 0.0f) allpad_s = 0;
  __syncthreads();
  int allpad = allpad_s;

  int n = blockIdx.x * 256 + tid;
  unsigned short* qp = qa + ((size_t)b * NPIX + n) * CV_ + h * DH_;
  float qv[32];
#pragma unroll
  for (int i = 0; i < 8; ++i) {
    ushort4 u = reinterpret_cast<const ushort4*>(qp)[i];
    qv[4 * i] = bf2f(u.x); qv[4 * i + 1] = bf2f(u.y);
    qv[4 * i + 2] = bf2f(u.z); qv[4 * i + 3] = bf2f(u.w);
  }
  float ss = 0.f;
#pragma unroll
  for (int d = 0; d < 32; ++d) ss += qv[d] * qv[d];
  float ls = *ls_ptr;
  ls = fminf(fmaxf(ls, -2.0f), 2.0f);
  float scale = expf(ls) * 0.17677669529663687f;   // exp(clip(ls)) / sqrt(32)
  float rn = scale / fmaxf(sqrtf(ss), 1e-6f);
#pragma unroll
  for (int d = 0; d < 32; ++d) qv[d] *= rn;

  float tv0 = -INFINITY, tv1 = -INFINITY, tv2 = -INFINITY, tv3 = -INFINITY, tv4 = -INFINITY;
  int   ti0 = 0, ti1 = 0, ti2 = 0, ti3 = 0, ti4 = 0;
  for (int t = 0; t < TT; ++t) {
    if (ps[t] != 0.0f) continue;               // padded -> sim = -inf
    const float* kp = &ks[t * 32];
    float sdot = 0.f;
#pragma unroll
    for (int d = 0; d < 32; ++d) sdot += qv[d] * kp[d];
    if (sdot > tv4) {
      if (sdot > tv0) {
        tv4=tv3; ti4=ti3; tv3=tv2; ti3=ti2; tv2=tv1; ti2=ti1; tv1=tv0; ti1=ti0; tv0=sdot; ti0=t;
      } else if (sdot > tv1) {
        tv4=tv3; ti4=ti3; tv3=tv2; ti3=ti2; tv2=tv1; ti2=ti1; tv1=sdot; ti1=t;
      } else if (sdot > tv2) {
        tv4=tv3; ti4=ti3; tv3=tv2; ti3=ti2; tv2=sdot; ti2=t;
      } else if (sdot > tv3) {
        tv4=tv3; ti4=ti3; tv3=sdot; ti3=t;
      } else {
        tv4=sdot; ti4=t;
      }
    }
  }
  float o[32];
#pragma unroll
  for (int d = 0; d < 32; ++d) o[d] = 0.f;
  if (!allpad && tv0 > -INFINITY) {
    float e0 = 1.0f;
    float e1 = expf(tv1 - tv0);
    float e2 = expf(tv2 - tv0);
    float e3 = expf(tv3 - tv0);
    float e4 = expf(tv4 - tv0);
    float inv = 1.0f / (e0 + e1 + e2 + e3 + e4);
    const float* v0p = &vs[ti0 * 32]; const float* v1p = &vs[ti1 * 32];
    const float* v2p = &vs[ti2 * 32]; const float* v3p = &vs[ti3 * 32];
    const float* v4p = &vs[ti4 * 32];
#pragma unroll
    for (int d = 0; d < 32; ++d)
      o[d] = (e0 * v0p[d] + e1 * v1p[d] + e2 * v2p[d] + e3 * v3p[d] + e4 * v4p[d]) * inv;
  }
#pragma unroll
  for (int i = 0; i < 8; ++i) {
    ushort4 u;
    u.x = f2b(o[4 * i]);     u.y = f2b(o[4 * i + 1]);
    u.z = f2b(o[4 * i + 2]); u.w = f2b(o[4 * i + 3]);
    reinterpret_cast<ushort4*>(qp)[i] = u;
  }
}

extern "C" void kernel_launch(void* const* d_in, const int* in_sizes, int n_in,
                              void* d_out, int out_size, void* d_ws, size_t ws_size,
                              hipStream_t stream) {
  const float* visual = (const float*)d_in[0];
  const float* text   = (const float*)d_in[1];
  const float* Wq  = (const float*)d_in[2];
  const float* bq  = (const float*)d_in[3];
  const float* Wk  = (const float*)d_in[4];
  const float* bk  = (const float*)d_in[5];
  const float* Wv  = (const float*)d_in[6];
  const float* bv  = (const float*)d_in[7];
  const float* Wo  = (const float*)d_in[8];
  const float* bo  = (const float*)d_in[9];
  const float* g1  = (const float*)d_in[10];
  const float* b1  = (const float*)d_in[11];
  const float* g2  = (const float*)d_in[12];
  const float* b2  = (const float*)d_in[13];
  const float* W1  = (const float*)d_in[14];
  const float* bf1 = (const float*)d_in[15];
  const float* W2  = (const float*)d_in[16];
  const float* bff2 = (const float*)d_in[17];
  const float* lsc = (const float*)d_in[18];
  const float* alp = (const float*)d_in[19];

  char* ws = (char*)d_ws;
  size_t off = 0;
  auto alloc = [&](size_t bytes) -> char* {
    char* p = ws + off;
    off += (bytes + 255) & ~(size_t)255;
    return p;
  };
  unsigned short* WqT = (unsigned short*)alloc((size_t)65536 * 2);
  unsigned short* WkT = (unsigned short*)alloc((size_t)131072 * 2);
  unsigned short* WvT = (unsigned short*)alloc((size_t)131072 * 2);
  unsigned short* WoT = (unsigned short*)alloc((size_t)65536 * 2);
  unsigned short* W1T = (unsigned short*)alloc((size_t)262144 * 2);
  unsigned short* W2T = (unsigned short*)alloc((size_t)262144 * 2);
  float*          kbuf = (float*)alloc((size_t)BT_ * CV_ * 4);
  unsigned short* vbuf = (unsigned short*)alloc((size_t)BT_ * CV_ * 2);
  float*          padb = (float*)alloc((size_t)BT_ * 4);
  // Union region U (33.55 MB):
  //   xbuf bf16 @U+0       (16.78 MB, live steps 2-7; step 7 rewrites as y0 in place)
  //   qbuf bf16 @U+16.78MB (16.78 MB, live steps 3-7; attn rewrites in place)
  //   hbuf bf16 @U+0       (33.55 MB per M-half, steps 9-10; x/q dead then)
  // y (LN2 out, fp32) lives in d_out: A of FFN1 (converted on load), resid of FFN2.
  char* U = ws + off;                      // total ws ~= 36.3 MB
  unsigned short* xbuf  = (unsigned short*)U;
  unsigned short* qbuf  = (unsigned short*)(U + 16777216);
  unsigned short* hbuf  = (unsigned short*)U;
  float*          ybuf  = (float*)d_out;

  // 1. weight convert+transpose (fp32 (K,N) -> bf16 (N,K))
  convT_k<<<256,  256, 0, stream>>>(Wq, WqT, 256, 256);
  convT_k<<<512,  256, 0, stream>>>(Wk, WkT, 512, 256);
  convT_k<<<512,  256, 0, stream>>>(Wv, WvT, 512, 256);
  convT_k<<<256,  256, 0, stream>>>(Wo, WoT, 256, 256);
  convT_k<<<1024, 256, 0, stream>>>(W1, W1T, 256, 1024);
  convT_k<<<1024, 256, 0, stream>>>(W2, W2T, 1024, 256);
  // 2. LN1: visual (fp32) -> x (bf16)
  ln_kernel<<<8192, 256, 0, stream>>>(visual, g1, b1, xbuf, MROW, 1);
  // 3. q = x @ Wq + bq  (bf16 out)
  gemm_bt<<<dim3(512, 4), 256, 0, stream>>>(xbuf, WqT, bq, nullptr, nullptr,
                                            qbuf, MROW, 256, 256, 0);
  // 4. k,v = text @ Wk/Wv + b  (A fp32; k fp32 out for norm precision, v bf16)
  gemm_bt<<<dim3(10, 4), 256, 0, stream>>>(text, WkT, bk, nullptr, nullptr,
                                           kbuf, BT_, 256, 512, 5);
  gemm_bt<<<dim3(10, 4), 256, 0, stream>>>(text, WvT, bv, nullptr, nullptr,
                                           vbuf, BT_, 256, 512, 4);
  // 5. k l2norm + pad mask
  kv_post<<<BT_, 256, 0, stream>>>(text, kbuf, padb);
  // 6. attention: qbuf (q) -> qbuf (aligned), in place
  attn_kernel<<<dim3(16, NH_, NB), 256, 0, stream>>>(qbuf, kbuf, vbuf, padb, lsc);
  // 7. y0 = x + alpha * (aligned @ Wo + bo)  -> overwrite xbuf (resid aliases out)
  gemm_bt<<<dim3(512, 4), 256, 0, stream>>>(qbuf, WoT, bo, xbuf, alp,
                                            xbuf, MROW, 256, 256, 0);
  // 8. LN2: y0 (bf16) -> y (fp32, in d_out)
  ln_kernel<<<8192, 256, 0, stream>>>(xbuf, g2, b2, ybuf, MROW, 2);
  // 9+10. FFN in two M-halves so hdn (bf16) fits over dead x|q region
  for (int half = 0; half < 2; ++half) {
    const float* yh = ybuf + (size_t)half * 16384 * CV_;
    // hdn = gelu(y @ W1 + b1)   (A fp32 convert-on-load, GELU)
    gemm_bt<<<dim3(256, 16), 256, 0, stream>>>(yh, W1T, bf1, nullptr, nullptr,
                                               hbuf, 16384, 1024, 256, 6);
    // out = y + (hdn @ W2 + b2) (resid fp32 aliases out elementwise — safe)
    gemm_bt<<<dim3(256, 4), 256, 0, stream>>>(hbuf, W2T, bff2, yh, nullptr,
                                              (void*)yh, 16384, 256, 1024, 9);
  }
}

// Round 4
// 405.175 us; speedup vs baseline: 1.0000x; 1.0000x over previous
//
#include <hip/hip_runtime.h>
#include <math.h>

// Problem constants
#define NB   8
#define NPIX 4096          // H*W
#define MROW 32768         // B*H*W
#define CV_  256
#define TT   77
#define CT_  512
#define NH_  8
#define DH_  32
#define BT_  616           // B*T

typedef __bf16 bf16x8 __attribute__((ext_vector_type(8)));
typedef float  f32x4  __attribute__((ext_vector_type(4)));

__device__ __forceinline__ float bf2f(unsigned short u) {
  return __uint_as_float(((unsigned)u) << 16);
}
__device__ __forceinline__ unsigned short f2b(float f) {
  unsigned u = __float_as_uint(f);
  return (unsigned short)((u + 0x7FFFu + ((u >> 16) & 1u)) >> 16);
}
__device__ __forceinline__ unsigned pack2(float lo, float hi) {
  return ((unsigned)f2b(hi) << 16) | (unsigned)f2b(lo);
}
__device__ __forceinline__ void async_copy16(const unsigned short* g,
                                             unsigned short* l) {
  __builtin_amdgcn_global_load_lds(
      (const __attribute__((address_space(1))) void*)g,
      (__attribute__((address_space(3))) void*)l, 16, 0, 0);
}

// ------- fused convert+transpose of all 6 weights (fp32 (K,N)->bf16 (N,K))
__global__ __launch_bounds__(256) void convT_all(
    const float* __restrict__ s0, const float* __restrict__ s1,
    const float* __restrict__ s2, const float* __restrict__ s3,
    const float* __restrict__ s4, const float* __restrict__ s5,
    unsigned short* __restrict__ d0, unsigned short* __restrict__ d1,
    unsigned short* __restrict__ d2, unsigned short* __restrict__ d3,
    unsigned short* __restrict__ d4, unsigned short* __restrict__ d5) {
  int gi = blockIdx.x * 256 + threadIdx.x;
  const float* src; unsigned short* dst; int R, C, idx;
  if      (gi < 65536)  { src=s0; dst=d0; R=256;  C=256;  idx=gi; }
  else if (gi < 196608) { src=s1; dst=d1; R=512;  C=256;  idx=gi-65536; }
  else if (gi < 327680) { src=s2; dst=d2; R=512;  C=256;  idx=gi-196608; }
  else if (gi < 393216) { src=s3; dst=d3; R=256;  C=256;  idx=gi-327680; }
  else if (gi < 655360) { src=s4; dst=d4; R=256;  C=1024; idx=gi-393216; }
  else if (gi < 917504) { src=s5; dst=d5; R=1024; C=256;  idx=gi-655360; }
  else return;
  int r = idx / C, c = idx - r * C;
  dst[(size_t)c * R + r] = f2b(src[idx]);
}

// ---------------- LayerNorm over last dim (256); one wave per row --------
// flags: bit0 = src fp32 (else bf16), bit1 = dst fp32 (else bf16)
__global__ __launch_bounds__(256) void ln_kernel(
    const void* __restrict__ src, const float* __restrict__ g,
    const float* __restrict__ b, void* __restrict__ dst, int rows, int flags) {
  int wave = threadIdx.x >> 6, lane = threadIdx.x & 63;
  int row = blockIdx.x * 4 + wave;
  if (row >= rows) return;
  size_t base = (size_t)row * 256 + lane * 4;
  float v0, v1, v2, v3;
  if (flags & 1) {
    float4 f = *reinterpret_cast<const float4*>((const float*)src + base);
    v0 = f.x; v1 = f.y; v2 = f.z; v3 = f.w;
  } else {
    ushort4 u = *reinterpret_cast<const ushort4*>((const unsigned short*)src + base);
    v0 = bf2f(u.x); v1 = bf2f(u.y); v2 = bf2f(u.z); v3 = bf2f(u.w);
  }
  float s = v0 + v1 + v2 + v3;
  float q = v0 * v0 + v1 * v1 + v2 * v2 + v3 * v3;
#pragma unroll
  for (int off = 1; off < 64; off <<= 1) {
    s += __shfl_xor(s, off);
    q += __shfl_xor(q, off);
  }
  float mean = s * (1.0f / 256.0f);
  float var  = q * (1.0f / 256.0f) - mean * mean;
  float rstd = rsqrtf(var + 1e-5f);
  float4 gv = *reinterpret_cast<const float4*>(g + lane * 4);
  float4 bv = *reinterpret_cast<const float4*>(b + lane * 4);
  float o0 = (v0 - mean) * rstd * gv.x + bv.x;
  float o1 = (v1 - mean) * rstd * gv.y + bv.y;
  float o2 = (v2 - mean) * rstd * gv.z + bv.z;
  float o3 = (v3 - mean) * rstd * gv.w + bv.w;
  if (flags & 2) {
    *reinterpret_cast<float4*>((float*)dst + base) = make_float4(o0, o1, o2, o3);
  } else {
    ushort4 o;
    o.x = f2b(o0); o.y = f2b(o1); o.z = f2b(o2); o.w = f2b(o3);
    *reinterpret_cast<ushort4*>((unsigned short*)dst + base) = o;
  }
}

// ------------- fast MFMA GEMM (m97 structure): C[M,N] = A @ Bt^T ---------
// BM=128, BK=32, BN template (64/128). 256 thr / 4 waves, each wave 64x(BN/2).
// Requires M%128==0, N%BN==0, K%32==0.
// flags: bit0 out fp32, bit1 exact-GELU, bit2 A fp32 (VGPR staging), bit3 resid fp32
// resid may alias out elementwise.
template <int BN>
__global__ __launch_bounds__(256) void gemm_fast(
    const void* __restrict__ A, const unsigned short* __restrict__ Bt,
    const float* __restrict__ bias, const void* resid,
    const float* __restrict__ alpha_ptr, void* out,
    int M, int N, int K, int flags) {
  constexpr int NI  = BN / 32;       // n-frags per wave
  constexpr int CHB = BN / 16;       // 1KB chunks in B tile
  __shared__ unsigned short lA[128 * 32];   // unpadded: global_load_lds layout
  __shared__ unsigned short lB[BN * 32];
  int tid = threadIdx.x;
  int bm = blockIdx.x * 128, bn = blockIdx.y * BN;
  int lane = tid & 63, wave = tid >> 6;
  int wm = (wave & 1) * 64, wn = (wave >> 1) * (BN / 2);
  int l15 = lane & 15, quad = lane >> 4;
  int crow = lane >> 2, ccol = (lane & 3) * 8;   // async chunk mapping
  f32x4 acc[4][NI] = {};
  for (int k0 = 0; k0 < K; k0 += 32) {
    if (flags & 4) {                  // fp32 A -> convert+ds_write staging
      const float* Af = (const float*)A;
      int r0 = tid >> 2, c8 = (tid & 3) * 8;
#pragma unroll
      for (int rr = 0; rr < 128; rr += 64) {
        const float* p = Af + (size_t)(bm + r0 + rr) * K + k0 + c8;
        float4 f0 = *reinterpret_cast<const float4*>(p);
        float4 f1 = *reinterpret_cast<const float4*>(p + 4);
        uint4 pk;
        pk.x = pack2(f0.x, f0.y); pk.y = pack2(f0.z, f0.w);
        pk.z = pack2(f1.x, f1.y); pk.w = pack2(f1.z, f1.w);
        *reinterpret_cast<uint4*>(&lA[(r0 + rr) * 32 + c8]) = pk;
      }
    } else {                          // bf16 A -> async global->LDS (16B/lane)
      const unsigned short* Ab = (const unsigned short*)A;
#pragma unroll
      for (int ch = 0; ch < 2; ++ch) {
        int c = wave * 2 + ch;        // 8 chunks of 16 rows
        async_copy16(Ab + (size_t)(bm + c * 16 + crow) * K + k0 + ccol,
                     &lA[c * 512]);
      }
    }
#pragma unroll
    for (int ch = wave; ch < CHB; ch += 4)
      async_copy16(Bt + (size_t)(bn + ch * 16 + crow) * K + k0 + ccol,
                   &lB[ch * 512]);
    __syncthreads();
    bf16x8 af[4], bf[NI];
#pragma unroll
    for (int mi = 0; mi < 4; ++mi)
      af[mi] = *reinterpret_cast<const bf16x8*>(&lA[(wm + mi * 16 + l15) * 32 + quad * 8]);
#pragma unroll
    for (int ni = 0; ni < NI; ++ni)
      bf[ni] = *reinterpret_cast<const bf16x8*>(&lB[(wn + ni * 16 + l15) * 32 + quad * 8]);
#pragma unroll
    for (int mi = 0; mi < 4; ++mi)
#pragma unroll
      for (int ni = 0; ni < NI; ++ni)
        acc[mi][ni] = __builtin_amdgcn_mfma_f32_16x16x32_bf16(af[mi], bf[ni],
                                                              acc[mi][ni], 0, 0, 0);
    __syncthreads();
  }
  float alpha = alpha_ptr ? *alpha_ptr : 1.0f;
#pragma unroll
  for (int mi = 0; mi < 4; ++mi) {
#pragma unroll
    for (int ni = 0; ni < NI; ++ni) {
      int gcol = bn + wn + ni * 16 + l15;
      float bsf = bias ? bias[gcol] : 0.0f;
#pragma unroll
      for (int r = 0; r < 4; ++r) {
        int grow = bm + wm + mi * 16 + quad * 4 + r;
        float v = acc[mi][ni][r] + bsf;
        if (flags & 2) v = 0.5f * v * (1.0f + erff(v * 0.70710678118654752f));
        size_t oi = (size_t)grow * N + gcol;
        if (resid) {
          float rv = (flags & 8) ? ((const float*)resid)[oi]
                                 : bf2f(((const unsigned short*)resid)[oi]);
          v = rv + alpha * v;
        }
        if (flags & 1) ((float*)out)[oi] = v;
        else           ((unsigned short*)out)[oi] = f2b(v);
      }
    }
  }
}

// ---------------- small GEMM (k/v proj): C[M,N] = A_f32 @ Bt^T -----------
// 64x64 tile; flags: bit0 out fp32
__global__ __launch_bounds__(256) void gemm_small(
    const float* __restrict__ A, const unsigned short* __restrict__ Bt,
    const float* __restrict__ bias, void* out, int M, int N, int K, int flags) {
  __shared__ unsigned short lA[64 * 40];
  __shared__ unsigned short lB[64 * 40];
  int tid = threadIdx.x;
  int bm = blockIdx.x * 64, bn = blockIdx.y * 64;
  int srow = tid >> 2, sc8 = (tid & 3) * 8;
  int lane = tid & 63, wave = tid >> 6;
  int wm = (wave & 1) * 32, wn = (wave >> 1) * 32;
  int l15 = lane & 15, quad = lane >> 4;
  f32x4 acc[2][2] = {};
  int gm = bm + srow, gn = bn + srow;
  const bool aok = (gm < M);
  for (int k0 = 0; k0 < K; k0 += 32) {
    uint4 apk = make_uint4(0, 0, 0, 0);
    if (aok) {
      const float* Af = A + (size_t)gm * K + k0 + sc8;
      float4 f0 = *reinterpret_cast<const float4*>(Af);
      float4 f1 = *reinterpret_cast<const float4*>(Af + 4);
      apk.x = pack2(f0.x, f0.y); apk.y = pack2(f0.z, f0.w);
      apk.z = pack2(f1.x, f1.y); apk.w = pack2(f1.z, f1.w);
    }
    uint4 bpk = *reinterpret_cast<const uint4*>(Bt + (size_t)gn * K + k0 + sc8);
    *reinterpret_cast<uint4*>(&lA[srow * 40 + sc8]) = apk;
    *reinterpret_cast<uint4*>(&lB[srow * 40 + sc8]) = bpk;
    __syncthreads();
    bf16x8 a0 = *reinterpret_cast<const bf16x8*>(&lA[(wm + l15) * 40 + quad * 8]);
    bf16x8 a1 = *reinterpret_cast<const bf16x8*>(&lA[(wm + 16 + l15) * 40 + quad * 8]);
    bf16x8 b0 = *reinterpret_cast<const bf16x8*>(&lB[(wn + l15) * 40 + quad * 8]);
    bf16x8 b1 = *reinterpret_cast<const bf16x8*>(&lB[(wn + 16 + l15) * 40 + quad * 8]);
    acc[0][0] = __builtin_amdgcn_mfma_f32_16x16x32_bf16(a0, b0, acc[0][0], 0, 0, 0);
    acc[0][1] = __builtin_amdgcn_mfma_f32_16x16x32_bf16(a0, b1, acc[0][1], 0, 0, 0);
    acc[1][0] = __builtin_amdgcn_mfma_f32_16x16x32_bf16(a1, b0, acc[1][0], 0, 0, 0);
    acc[1][1] = __builtin_amdgcn_mfma_f32_16x16x32_bf16(a1, b1, acc[1][1], 0, 0, 0);
    __syncthreads();
  }
#pragma unroll
  for (int mt = 0; mt < 2; ++mt) {
#pragma unroll
    for (int nt = 0; nt < 2; ++nt) {
      int gcol = bn + wn + nt * 16 + l15;
      float bsf = bias ? bias[gcol] : 0.0f;
#pragma unroll
      for (int r = 0; r < 4; ++r) {
        int grow = bm + wm + mt * 16 + quad * 4 + r;
        if (grow >= M) continue;
        float v = acc[mt][nt][r] + bsf;
        size_t oi = (size_t)grow * N + gcol;
        if (flags & 1) ((float*)out)[oi] = v;
        else           ((unsigned short*)out)[oi] = f2b(v);
      }
    }
  }
}

// ---------------- k l2norm (per 32-dh group, in place) + pad mask --------
__global__ __launch_bounds__(256) void kv_post(
    const float* __restrict__ text, float* __restrict__ k,
    float* __restrict__ pad) {
  int bt = blockIdx.x;
  int tid = threadIdx.x;
  __shared__ float red[4];
  const float* tr = text + (size_t)bt * CT_;
  float s = fabsf(tr[tid]) + fabsf(tr[tid + 256]);
#pragma unroll
  for (int off = 1; off < 64; off <<= 1) s += __shfl_xor(s, off);
  if ((tid & 63) == 0) red[tid >> 6] = s;
  __syncthreads();
  if (tid == 0) {
    float tot = red[0] + red[1] + red[2] + red[3];
    pad[bt] = (tot <= 1e-6f) ? 1.0f : 0.0f;
  }
  float v = k[(size_t)bt * CV_ + tid];
  float ss = v * v;
#pragma unroll
  for (int off = 1; off < 32; off <<= 1) ss += __shfl_xor(ss, off);
  float n = sqrtf(ss);
  k[(size_t)bt * CV_ + tid] = v / fmaxf(n, 1e-6f);
}

// ---------------- attention: top-5 masked cosine attention ---------------
// grid (16, NH, B), 256 thr; thread -> query n = bx*256+tid of head h, batch b
// qa: in = q (bf16), out = aligned, IN PLACE (each thread owns its 32-d slice)
#define VSTRIDE 33    // pad V rows: bank (ti*33+d)%32 = (ti+d)%32 -> <=3-way
__global__ __launch_bounds__(256) void attn_kernel(
    unsigned short* qa, const float* __restrict__ k,
    const unsigned short* __restrict__ v, const float* __restrict__ pad,
    const float* __restrict__ ls_ptr) {
  __shared__ float ks[TT * DH_];
  __shared__ float vs[TT * VSTRIDE];
  __shared__ float ps[TT];
  __shared__ int allpad_s;
  int tid = threadIdx.x;
  int h = blockIdx.y, b = blockIdx.z;
  size_t kvbase = (size_t)b * TT * CV_ + h * DH_;
  for (int idx = tid; idx < TT * DH_; idx += 256) {
    int t = idx >> 5, d = idx & 31;
    ks[idx] = k[kvbase + (size_t)t * CV_ + d];
    vs[t * VSTRIDE + d] = bf2f(v[kvbase + (size_t)t * CV_ + d]);
  }
  if (tid < TT) ps[tid] = pad[b * TT + tid];
  if (tid == 0) allpad_s = 1;
  __syncthreads();
  if (tid < TT && ps[tid] == 0.0f) allpad_s = 0;
  __syncthreads();
  int allpad = allpad_s;

  int n = blockIdx.x * 256 + tid;
  unsigned short* qp = qa + ((size_t)b * NPIX + n) * CV_ + h * DH_;
  float qv[32];
#pragma unroll
  for (int i = 0; i < 8; ++i) {
    ushort4 u = reinterpret_cast<const ushort4*>(qp)[i];
    qv[4 * i] = bf2f(u.x); qv[4 * i + 1] = bf2f(u.y);
    qv[4 * i + 2] = bf2f(u.z); qv[4 * i + 3] = bf2f(u.w);
  }
  float ss = 0.f;
#pragma unroll
  for (int d = 0; d < 32; ++d) ss += qv[d] * qv[d];
  float ls = *ls_ptr;
  ls = fminf(fmaxf(ls, -2.0f), 2.0f);
  float scale = expf(ls) * 0.17677669529663687f;   // exp(clip(ls)) / sqrt(32)
  float rn = scale / fmaxf(sqrtf(ss), 1e-6f);
#pragma unroll
  for (int d = 0; d < 32; ++d) qv[d] *= rn;

  float tv0 = -INFINITY, tv1 = -INFINITY, tv2 = -INFINITY, tv3 = -INFINITY, tv4 = -INFINITY;
  int   ti0 = 0, ti1 = 0, ti2 = 0, ti3 = 0, ti4 = 0;
  for (int t = 0; t < TT; ++t) {
    if (ps[t] != 0.0f) continue;               // uniform branch (pad tokens)
    const float* kp = &ks[t * 32];
    float sdot = 0.f;
#pragma unroll
    for (int d = 0; d < 32; ++d) sdot += qv[d] * kp[d];
    // branchless sorted insert (compute all compares on OLD values, shift down)
    bool g0 = sdot > tv0, g1 = sdot > tv1, g2 = sdot > tv2,
         g3 = sdot > tv3, g4 = sdot > tv4;
    tv4 = g4 ? (g3 ? tv3 : sdot) : tv4;  ti4 = g4 ? (g3 ? ti3 : t) : ti4;
    tv3 = g3 ? (g2 ? tv2 : sdot) : tv3;  ti3 = g3 ? (g2 ? ti2 : t) : ti3;
    tv2 = g2 ? (g1 ? tv1 : sdot) : tv2;  ti2 = g2 ? (g1 ? ti1 : t) : ti2;
    tv1 = g1 ? (g0 ? tv0 : sdot) : tv1;  ti1 = g1 ? (g0 ? ti0 : t) : ti1;
    tv0 = g0 ? sdot : tv0;               ti0 = g0 ? t : ti0;
  }
  float o[32];
#pragma unroll
  for (int d = 0; d < 32; ++d) o[d] = 0.f;
  if (!allpad && tv0 > -INFINITY) {
    float e0 = 1.0f;
    float e1 = expf(tv1 - tv0);
    float e2 = expf(tv2 - tv0);
    float e3 = expf(tv3 - tv0);
    float e4 = expf(tv4 - tv0);
    float inv = 1.0f / (e0 + e1 + e2 + e3 + e4);
    const float* v0p = &vs[ti0 * VSTRIDE]; const float* v1p = &vs[ti1 * VSTRIDE];
    const float* v2p = &vs[ti2 * VSTRIDE]; const float* v3p = &vs[ti3 * VSTRIDE];
    const float* v4p = &vs[ti4 * VSTRIDE];
#pragma unroll
    for (int d = 0; d < 32; ++d)
      o[d] = (e0 * v0p[d] + e1 * v1p[d] + e2 * v2p[d] + e3 * v3p[d] + e4 * v4p[d]) * inv;
  }
#pragma unroll
  for (int i = 0; i < 8; ++i) {
    ushort4 u;
    u.x = f2b(o[4 * i]);     u.y = f2b(o[4 * i + 1]);
    u.z = f2b(o[4 * i + 2]); u.w = f2b(o[4 * i + 3]);
    reinterpret_cast<ushort4*>(qp)[i] = u;
  }
}

extern "C" void kernel_launch(void* const* d_in, const int* in_sizes, int n_in,
                              void* d_out, int out_size, void* d_ws, size_t ws_size,
                              hipStream_t stream) {
  const float* visual = (const float*)d_in[0];
  const float* text   = (const float*)d_in[1];
  const float* Wq  = (const float*)d_in[2];
  const float* bq  = (const float*)d_in[3];
  const float* Wk  = (const float*)d_in[4];
  const float* bk  = (const float*)d_in[5];
  const float* Wv  = (const float*)d_in[6];
  const float* bv  = (const float*)d_in[7];
  const float* Wo  = (const float*)d_in[8];
  const float* bo  = (const float*)d_in[9];
  const float* g1  = (const float*)d_in[10];
  const float* b1  = (const float*)d_in[11];
  const float* g2  = (const float*)d_in[12];
  const float* b2  = (const float*)d_in[13];
  const float* W1  = (const float*)d_in[14];
  const float* bf1 = (const float*)d_in[15];
  const float* W2  = (const float*)d_in[16];
  const float* bff2 = (const float*)d_in[17];
  const float* lsc = (const float*)d_in[18];
  const float* alp = (const float*)d_in[19];

  char* ws = (char*)d_ws;
  size_t off = 0;
  auto alloc = [&](size_t bytes) -> char* {
    char* p = ws + off;
    off += (bytes + 255) & ~(size_t)255;
    return p;
  };
  unsigned short* WqT = (unsigned short*)alloc((size_t)65536 * 2);
  unsigned short* WkT = (unsigned short*)alloc((size_t)131072 * 2);
  unsigned short* WvT = (unsigned short*)alloc((size_t)131072 * 2);
  unsigned short* WoT = (unsigned short*)alloc((size_t)65536 * 2);
  unsigned short* W1T = (unsigned short*)alloc((size_t)262144 * 2);
  unsigned short* W2T = (unsigned short*)alloc((size_t)262144 * 2);
  float*          kbuf = (float*)alloc((size_t)BT_ * CV_ * 4);
  unsigned short* vbuf = (unsigned short*)alloc((size_t)BT_ * CV_ * 2);
  float*          padb = (float*)alloc((size_t)BT_ * 4);
  // Union region U (33.55 MB):
  //   xbuf bf16 @U+0       (16.78 MB, live steps 2-7; step 7 rewrites y0 in place)
  //   qbuf bf16 @U+16.78MB (16.78 MB, live steps 3-7; attn rewrites in place)
  //   hbuf bf16 @U+0       (33.55 MB per M-half, FFN; x/q dead then)
  // y (LN2 out, fp32) lives in d_out: A of FFN1 (convert-on-load), resid of FFN2.
  char* U = ws + off;                      // total ws ~= 36.3 MB
  unsigned short* xbuf = (unsigned short*)U;
  unsigned short* qbuf = (unsigned short*)(U + 16777216);
  unsigned short* hbuf = (unsigned short*)U;
  float*          ybuf = (float*)d_out;

  // 1. all weight convert+transposes in one dispatch
  convT_all<<<3584, 256, 0, stream>>>(Wq, Wk, Wv, Wo, W1, W2,
                                      WqT, WkT, WvT, WoT, W1T, W2T);
  // 2. LN1: visual (fp32) -> x (bf16)
  ln_kernel<<<8192, 256, 0, stream>>>(visual, g1, b1, xbuf, MROW, 1);
  // 3. q = x @ Wq + bq  (bf16 out, fast path)
  gemm_fast<128><<<dim3(256, 2), 256, 0, stream>>>(
      xbuf, WqT, bq, nullptr, nullptr, qbuf, MROW, 256, 256, 0);
  // 4. k,v = text @ Wk/Wv + b  (fp32 A; k fp32 out, v bf16)
  gemm_small<<<dim3(10, 4), 256, 0, stream>>>(text, WkT, bk, kbuf, BT_, 256, 512, 1);
  gemm_small<<<dim3(10, 4), 256, 0, stream>>>(text, WvT, bv, vbuf, BT_, 256, 512, 0);
  // 5. k l2norm + pad mask
  kv_post<<<BT_, 256, 0, stream>>>(text, kbuf, padb);
  // 6. attention: qbuf (q) -> qbuf (aligned), in place
  attn_kernel<<<dim3(16, NH_, NB), 256, 0, stream>>>(qbuf, kbuf, vbuf, padb, lsc);
  // 7. y0 = x + alpha * (aligned @ Wo + bo)  -> overwrite xbuf in place
  gemm_fast<128><<<dim3(256, 2), 256, 0, stream>>>(
      qbuf, WoT, bo, xbuf, alp, xbuf, MROW, 256, 256, 0);
  // 8. LN2: y0 (bf16) -> y (fp32, in d_out)
  ln_kernel<<<8192, 256, 0, stream>>>(xbuf, g2, b2, ybuf, MROW, 2);
  // 9+10. FFN in two M-halves so hdn (bf16, 33.55 MB) overlays dead x|q
  for (int half = 0; half < 2; ++half) {
    const float* yh = ybuf + (size_t)half * 16384 * CV_;
    // hdn = gelu(y @ W1 + b1)  (A fp32 convert-on-load, GELU, bf16 out)
    gemm_fast<128><<<dim3(128, 8), 256, 0, stream>>>(
        yh, W1T, bf1, nullptr, nullptr, hbuf, 16384, 1024, 256, 2 | 4);
    // out = y + (hdn @ W2 + b2)  (BN=64 -> 512 blocks; resid fp32 aliases out)
    gemm_fast<64><<<dim3(128, 4), 256, 0, stream>>>(
        hbuf, W2T, bff2, yh, nullptr, (void*)yh, 16384, 256, 1024, 1 | 8);
  }
}

// Round 5
// 363.207 us; speedup vs baseline: 1.1156x; 1.1155x over previous
//
#include <hip/hip_runtime.h>
#include <math.h>

// Problem constants
#define NB   8
#define NPIX 4096          // H*W
#define MROW 32768         // B*H*W
#define CV_  256
#define TT   77
#define CT_  512
#define NH_  8
#define DH_  32
#define BT_  616           // B*T

typedef __bf16 bf16x8 __attribute__((ext_vector_type(8)));
typedef float  f32x4  __attribute__((ext_vector_type(4)));
typedef float  f32x2  __attribute__((ext_vector_type(2)));

__device__ __forceinline__ float bf2f(unsigned short u) {
  return __uint_as_float(((unsigned)u) << 16);
}
__device__ __forceinline__ unsigned short f2b(float f) {
  unsigned u = __float_as_uint(f);
  return (unsigned short)((u + 0x7FFFu + ((u >> 16) & 1u)) >> 16);
}
__device__ __forceinline__ unsigned pack2(float lo, float hi) {
  return ((unsigned)f2b(hi) << 16) | (unsigned)f2b(lo);
}
__device__ __forceinline__ void async_copy16(const unsigned short* g,
                                             unsigned short* l) {
  __builtin_amdgcn_global_load_lds(
      (const __attribute__((address_space(1))) void*)g,
      (__attribute__((address_space(3))) void*)l, 16, 0, 0);
}

// ---- prep: LN1 (blocks 0..8191) + weight convT + kv bias (blocks 8192+) ----
__global__ __launch_bounds__(256) void prep_kernel(
    const float* __restrict__ visual, const float* __restrict__ g1,
    const float* __restrict__ b1, unsigned short* __restrict__ xbuf,
    const float* __restrict__ s0, const float* __restrict__ s1,
    const float* __restrict__ s2, const float* __restrict__ s3,
    const float* __restrict__ s4, const float* __restrict__ s5,
    unsigned short* __restrict__ d0, unsigned short* __restrict__ d1,
    unsigned short* __restrict__ d2, unsigned short* __restrict__ d3,
    unsigned short* __restrict__ d4, unsigned short* __restrict__ d5,
    const float* __restrict__ bk, const float* __restrict__ bv,
    float* __restrict__ bkv) {
  int bx = blockIdx.x;
  if (bx < 8192) {                       // LN1: visual fp32 -> x bf16
    int wave = threadIdx.x >> 6, lane = threadIdx.x & 63;
    int row = bx * 4 + wave;
    size_t base = (size_t)row * 256 + lane * 4;
    float4 f = *reinterpret_cast<const float4*>(visual + base);
    float v0 = f.x, v1 = f.y, v2 = f.z, v3 = f.w;
    float s = v0 + v1 + v2 + v3;
    float q = v0 * v0 + v1 * v1 + v2 * v2 + v3 * v3;
#pragma unroll
    for (int off = 1; off < 64; off <<= 1) {
      s += __shfl_xor(s, off);
      q += __shfl_xor(q, off);
    }
    float mean = s * (1.0f / 256.0f);
    float var  = q * (1.0f / 256.0f) - mean * mean;
    float rstd = rsqrtf(var + 1e-5f);
    float4 gv = *reinterpret_cast<const float4*>(g1 + lane * 4);
    float4 bv4 = *reinterpret_cast<const float4*>(b1 + lane * 4);
    ushort4 o;
    o.x = f2b((v0 - mean) * rstd * gv.x + bv4.x);
    o.y = f2b((v1 - mean) * rstd * gv.y + bv4.y);
    o.z = f2b((v2 - mean) * rstd * gv.z + bv4.z);
    o.w = f2b((v3 - mean) * rstd * gv.w + bv4.w);
    *reinterpret_cast<ushort4*>(xbuf + base) = o;
    return;
  }
  int gi = (bx - 8192) * 256 + threadIdx.x;
  const float* src; unsigned short* dst; int R, C, idx;
  if      (gi < 65536)  { src=s0; dst=d0; R=256;  C=256;  idx=gi; }
  else if (gi < 196608) { src=s1; dst=d1; R=512;  C=256;  idx=gi-65536; }
  else if (gi < 327680) { src=s2; dst=d2; R=512;  C=256;  idx=gi-196608; }
  else if (gi < 393216) { src=s3; dst=d3; R=256;  C=256;  idx=gi-327680; }
  else if (gi < 655360) { src=s4; dst=d4; R=256;  C=1024; idx=gi-393216; }
  else if (gi < 917504) { src=s5; dst=d5; R=1024; C=256;  idx=gi-655360; }
  else if (gi < 918016) {
    int i = gi - 917504;
    bkv[i] = (i < 256) ? bk[i] : bv[i - 256];
    return;
  } else return;
  int r = idx / C, c = idx - r * C;
  dst[(size_t)c * R + r] = f2b(src[idx]);
}

// ---------------- LayerNorm (LN2): bf16 src -> fp32 dst ------------------
__global__ __launch_bounds__(256) void ln_kernel(
    const unsigned short* __restrict__ src, const float* __restrict__ g,
    const float* __restrict__ b, float* __restrict__ dst) {
  int wave = threadIdx.x >> 6, lane = threadIdx.x & 63;
  int row = blockIdx.x * 4 + wave;
  size_t base = (size_t)row * 256 + lane * 4;
  ushort4 u = *reinterpret_cast<const ushort4*>(src + base);
  float v0 = bf2f(u.x), v1 = bf2f(u.y), v2 = bf2f(u.z), v3 = bf2f(u.w);
  float s = v0 + v1 + v2 + v3;
  float q = v0 * v0 + v1 * v1 + v2 * v2 + v3 * v3;
#pragma unroll
  for (int off = 1; off < 64; off <<= 1) {
    s += __shfl_xor(s, off);
    q += __shfl_xor(q, off);
  }
  float mean = s * (1.0f / 256.0f);
  float var  = q * (1.0f / 256.0f) - mean * mean;
  float rstd = rsqrtf(var + 1e-5f);
  float4 gv = *reinterpret_cast<const float4*>(g + lane * 4);
  float4 bv = *reinterpret_cast<const float4*>(b + lane * 4);
  float4 o;
  o.x = (v0 - mean) * rstd * gv.x + bv.x;
  o.y = (v1 - mean) * rstd * gv.y + bv.y;
  o.z = (v2 - mean) * rstd * gv.z + bv.z;
  o.w = (v3 - mean) * rstd * gv.w + bv.w;
  *reinterpret_cast<float4*>(dst + base) = o;
}

// ------------- fast MFMA GEMM (m97 structure): C[M,N] = A @ Bt^T ---------
// BM=128, BK=32, BN template (64/128). 256 thr / 4 waves.
// flags: bit0 out fp32, bit1 exact-GELU, bit2 A fp32 (VGPR staging), bit3 resid fp32
template <int BN>
__global__ __launch_bounds__(256) void gemm_fast(
    const void* __restrict__ A, const unsigned short* __restrict__ Bt,
    const float* __restrict__ bias, const void* resid,
    const float* __restrict__ alpha_ptr, void* out,
    int M, int N, int K, int flags) {
  constexpr int NI  = BN / 32;
  constexpr int CHB = BN / 16;
  __shared__ unsigned short lA[128 * 32];
  __shared__ unsigned short lB[BN * 32];
  int tid = threadIdx.x;
  int bm = blockIdx.x * 128, bn = blockIdx.y * BN;
  int lane = tid & 63, wave = tid >> 6;
  int wm = (wave & 1) * 64, wn = (wave >> 1) * (BN / 2);
  int l15 = lane & 15, quad = lane >> 4;
  int crow = lane >> 2, ccol = (lane & 3) * 8;
  f32x4 acc[4][NI] = {};
  for (int k0 = 0; k0 < K; k0 += 32) {
    if (flags & 4) {
      const float* Af = (const float*)A;
      int r0 = tid >> 2, c8 = (tid & 3) * 8;
#pragma unroll
      for (int rr = 0; rr < 128; rr += 64) {
        const float* p = Af + (size_t)(bm + r0 + rr) * K + k0 + c8;
        float4 f0 = *reinterpret_cast<const float4*>(p);
        float4 f1 = *reinterpret_cast<const float4*>(p + 4);
        uint4 pk;
        pk.x = pack2(f0.x, f0.y); pk.y = pack2(f0.z, f0.w);
        pk.z = pack2(f1.x, f1.y); pk.w = pack2(f1.z, f1.w);
        *reinterpret_cast<uint4*>(&lA[(r0 + rr) * 32 + c8]) = pk;
      }
    } else {
      const unsigned short* Ab = (const unsigned short*)A;
#pragma unroll
      for (int ch = 0; ch < 2; ++ch) {
        int c = wave * 2 + ch;
        async_copy16(Ab + (size_t)(bm + c * 16 + crow) * K + k0 + ccol,
                     &lA[c * 512]);
      }
    }
#pragma unroll
    for (int ch = wave; ch < CHB; ch += 4)
      async_copy16(Bt + (size_t)(bn + ch * 16 + crow) * K + k0 + ccol,
                   &lB[ch * 512]);
    __syncthreads();
    bf16x8 af[4], bf[NI];
#pragma unroll
    for (int mi = 0; mi < 4; ++mi)
      af[mi] = *reinterpret_cast<const bf16x8*>(&lA[(wm + mi * 16 + l15) * 32 + quad * 8]);
#pragma unroll
    for (int ni = 0; ni < NI; ++ni)
      bf[ni] = *reinterpret_cast<const bf16x8*>(&lB[(wn + ni * 16 + l15) * 32 + quad * 8]);
#pragma unroll
    for (int mi = 0; mi < 4; ++mi)
#pragma unroll
      for (int ni = 0; ni < NI; ++ni)
        acc[mi][ni] = __builtin_amdgcn_mfma_f32_16x16x32_bf16(af[mi], bf[ni],
                                                              acc[mi][ni], 0, 0, 0);
    __syncthreads();
  }
  float alpha = alpha_ptr ? *alpha_ptr : 1.0f;
#pragma unroll
  for (int mi = 0; mi < 4; ++mi) {
#pragma unroll
    for (int ni = 0; ni < NI; ++ni) {
      int gcol = bn + wn + ni * 16 + l15;
      float bsf = bias ? bias[gcol] : 0.0f;
#pragma unroll
      for (int r = 0; r < 4; ++r) {
        int grow = bm + wm + mi * 16 + quad * 4 + r;
        float v = acc[mi][ni][r] + bsf;
        if (flags & 2) v = 0.5f * v * (1.0f + erff(v * 0.70710678118654752f));
        size_t oi = (size_t)grow * N + gcol;
        if (resid) {
          float rv = (flags & 8) ? ((const float*)resid)[oi]
                                 : bf2f(((const unsigned short*)resid)[oi]);
          v = rv + alpha * v;
        }
        if (flags & 1) ((float*)out)[oi] = v;
        else           ((unsigned short*)out)[oi] = f2b(v);
      }
    }
  }
}

// ------ kv GEMM: [k|v](616,512) = text @ [WkT;WvT]^T, split fp32 outputs --
__global__ __launch_bounds__(256) void gemm_kv(
    const float* __restrict__ A, const unsigned short* __restrict__ Bt,
    const float* __restrict__ bias, float* __restrict__ kout,
    float* __restrict__ vout) {
  __shared__ unsigned short lA[64 * 40];
  __shared__ unsigned short lB[64 * 40];
  const int M = BT_, K = CT_;
  int tid = threadIdx.x;
  int bm = blockIdx.x * 64, bn = blockIdx.y * 64;
  int srow = tid >> 2, sc8 = (tid & 3) * 8;
  int lane = tid & 63, wave = tid >> 6;
  int wm = (wave & 1) * 32, wn = (wave >> 1) * 32;
  int l15 = lane & 15, quad = lane >> 4;
  f32x4 acc[2][2] = {};
  int gm = bm + srow, gn = bn + srow;
  const bool aok = (gm < M);
  for (int k0 = 0; k0 < K; k0 += 32) {
    uint4 apk = make_uint4(0, 0, 0, 0);
    if (aok) {
      const float* Af = A + (size_t)gm * K + k0 + sc8;
      float4 f0 = *reinterpret_cast<const float4*>(Af);
      float4 f1 = *reinterpret_cast<const float4*>(Af + 4);
      apk.x = pack2(f0.x, f0.y); apk.y = pack2(f0.z, f0.w);
      apk.z = pack2(f1.x, f1.y); apk.w = pack2(f1.z, f1.w);
    }
    uint4 bpk = *reinterpret_cast<const uint4*>(Bt + (size_t)gn * K + k0 + sc8);
    *reinterpret_cast<uint4*>(&lA[srow * 40 + sc8]) = apk;
    *reinterpret_cast<uint4*>(&lB[srow * 40 + sc8]) = bpk;
    __syncthreads();
    bf16x8 a0 = *reinterpret_cast<const bf16x8*>(&lA[(wm + l15) * 40 + quad * 8]);
    bf16x8 a1 = *reinterpret_cast<const bf16x8*>(&lA[(wm + 16 + l15) * 40 + quad * 8]);
    bf16x8 b0 = *reinterpret_cast<const bf16x8*>(&lB[(wn + l15) * 40 + quad * 8]);
    bf16x8 b1 = *reinterpret_cast<const bf16x8*>(&lB[(wn + 16 + l15) * 40 + quad * 8]);
    acc[0][0] = __builtin_amdgcn_mfma_f32_16x16x32_bf16(a0, b0, acc[0][0], 0, 0, 0);
    acc[0][1] = __builtin_amdgcn_mfma_f32_16x16x32_bf16(a0, b1, acc[0][1], 0, 0, 0);
    acc[1][0] = __builtin_amdgcn_mfma_f32_16x16x32_bf16(a1, b0, acc[1][0], 0, 0, 0);
    acc[1][1] = __builtin_amdgcn_mfma_f32_16x16x32_bf16(a1, b1, acc[1][1], 0, 0, 0);
    __syncthreads();
  }
#pragma unroll
  for (int mt = 0; mt < 2; ++mt) {
#pragma unroll
    for (int nt = 0; nt < 2; ++nt) {
      int gcol = bn + wn + nt * 16 + l15;
      float bsf = bias[gcol];
#pragma unroll
      for (int r = 0; r < 4; ++r) {
        int grow = bm + wm + mt * 16 + quad * 4 + r;
        if (grow >= M) continue;
        float v = acc[mt][nt][r] + bsf;
        if (gcol < 256) kout[(size_t)grow * 256 + gcol] = v;
        else            vout[(size_t)grow * 256 + gcol - 256] = v;
      }
    }
  }
}

// ---------------- attention: pad + k-norm + top-5 cosine attention -------
// grid (16, NH, B), 256 thr; thread -> query n = bx*256+tid of head h, batch b
// qa: in = q (bf16), out = aligned, IN PLACE (thread owns its 32-d slice)
#define KSTR 36   // 144B rows: 16B-aligned, conflict-free broadcast b128 reads
#define VSTR 33   // gather banks (t+d)%32
__global__ __launch_bounds__(256) void attn_kernel(
    unsigned short* qa, const float* __restrict__ k,
    const float* __restrict__ v, const float* __restrict__ text,
    const float* __restrict__ ls_ptr) {
  __shared__ float ks[TT * KSTR];
  __shared__ float vs[TT * VSTR];
  __shared__ float ps[TT];
  __shared__ int allpad_s;
  int tid = threadIdx.x;
  int h = blockIdx.y, b = blockIdx.z;
  size_t kvbase = (size_t)b * TT * CV_ + h * DH_;
  for (int idx = tid; idx < TT * DH_; idx += 256) {
    int t = idx >> 5, d = idx & 31;
    ks[t * KSTR + d] = k[kvbase + (size_t)t * CV_ + d];
    vs[t * VSTR + d] = v[kvbase + (size_t)t * CV_ + d];
  }
  if (tid == 0) allpad_s = 1;
  if (tid < TT) {     // pad mask from text (L2-resident)
    const float4* tp = reinterpret_cast<const float4*>(
        text + ((size_t)b * TT + tid) * CT_);
    float s = 0.f;
    for (int i = 0; i < 128; ++i) {
      float4 f = tp[i];
      s += fabsf(f.x) + fabsf(f.y) + fabsf(f.z) + fabsf(f.w);
    }
    ps[tid] = (s <= 1e-6f) ? 1.0f : 0.0f;
  }
  __syncthreads();
  if (tid < TT) {     // l2-normalize this head's k rows in LDS
    float ssum = 0.f;
#pragma unroll
    for (int d = 0; d < 32; ++d) { float x = ks[tid * KSTR + d]; ssum += x * x; }
    float sc = 1.0f / fmaxf(sqrtf(ssum), 1e-6f);
#pragma unroll
    for (int d = 0; d < 32; ++d) ks[tid * KSTR + d] *= sc;
    if (ps[tid] == 0.0f) allpad_s = 0;
  }
  __syncthreads();
  int allpad = allpad_s;

  int n = blockIdx.x * 256 + tid;
  unsigned short* qp = qa + ((size_t)b * NPIX + n) * CV_ + h * DH_;
  float qv[32];
#pragma unroll
  for (int i = 0; i < 8; ++i) {
    ushort4 u = reinterpret_cast<const ushort4*>(qp)[i];
    qv[4 * i] = bf2f(u.x); qv[4 * i + 1] = bf2f(u.y);
    qv[4 * i + 2] = bf2f(u.z); qv[4 * i + 3] = bf2f(u.w);
  }
  float ss = 0.f;
#pragma unroll
  for (int d = 0; d < 32; ++d) ss += qv[d] * qv[d];
  float ls = *ls_ptr;
  ls = fminf(fmaxf(ls, -2.0f), 2.0f);
  float scale = expf(ls) * 0.17677669529663687f;   // exp(clip)/sqrt(32)
  float rn = scale / fmaxf(sqrtf(ss), 1e-6f);
  f32x2 qv2[16];
#pragma unroll
  for (int j = 0; j < 16; ++j) {
    qv2[j][0] = qv[2 * j] * rn;
    qv2[j][1] = qv[2 * j + 1] * rn;
  }

  float tv0 = -INFINITY, tv1 = -INFINITY, tv2 = -INFINITY, tv3 = -INFINITY, tv4 = -INFINITY;
  int   ti0 = 0, ti1 = 0, ti2 = 0, ti3 = 0, ti4 = 0;
  for (int t = 0; t < TT; ++t) {
    if (ps[t] != 0.0f) continue;               // uniform branch
    const f32x2* kp = reinterpret_cast<const f32x2*>(&ks[t * KSTR]);
    f32x2 a2 = {0.f, 0.f};
#pragma unroll
    for (int j = 0; j < 16; ++j) a2 += qv2[j] * kp[j];   // v_pk_fma_f32
    float sdot = a2[0] + a2[1];
    bool g0 = sdot > tv0, g1 = sdot > tv1, g2 = sdot > tv2,
         g3 = sdot > tv3, g4 = sdot > tv4;
    tv4 = g4 ? (g3 ? tv3 : sdot) : tv4;  ti4 = g4 ? (g3 ? ti3 : t) : ti4;
    tv3 = g3 ? (g2 ? tv2 : sdot) : tv3;  ti3 = g3 ? (g2 ? ti2 : t) : ti3;
    tv2 = g2 ? (g1 ? tv1 : sdot) : tv2;  ti2 = g2 ? (g1 ? ti1 : t) : ti2;
    tv1 = g1 ? (g0 ? tv0 : sdot) : tv1;  ti1 = g1 ? (g0 ? ti0 : t) : ti1;
    tv0 = g0 ? sdot : tv0;               ti0 = g0 ? t : ti0;
  }
  float o[32];
#pragma unroll
  for (int d = 0; d < 32; ++d) o[d] = 0.f;
  if (!allpad && tv0 > -INFINITY) {
    float e0 = 1.0f;
    float e1 = expf(tv1 - tv0);
    float e2 = expf(tv2 - tv0);
    float e3 = expf(tv3 - tv0);
    float e4 = expf(tv4 - tv0);
    float inv = 1.0f / (e0 + e1 + e2 + e3 + e4);
    const float* v0p = &vs[ti0 * VSTR]; const float* v1p = &vs[ti1 * VSTR];
    const float* v2p = &vs[ti2 * VSTR]; const float* v3p = &vs[ti3 * VSTR];
    const float* v4p = &vs[ti4 * VSTR];
#pragma unroll
    for (int d = 0; d < 32; ++d)
      o[d] = (e0 * v0p[d] + e1 * v1p[d] + e2 * v2p[d] + e3 * v3p[d] + e4 * v4p[d]) * inv;
  }
#pragma unroll
  for (int i = 0; i < 8; ++i) {
    ushort4 u;
    u.x = f2b(o[4 * i]);     u.y = f2b(o[4 * i + 1]);
    u.z = f2b(o[4 * i + 2]); u.w = f2b(o[4 * i + 3]);
    reinterpret_cast<ushort4*>(qp)[i] = u;
  }
}

extern "C" void kernel_launch(void* const* d_in, const int* in_sizes, int n_in,
                              void* d_out, int out_size, void* d_ws, size_t ws_size,
                              hipStream_t stream) {
  const float* visual = (const float*)d_in[0];
  const float* text   = (const float*)d_in[1];
  const float* Wq  = (const float*)d_in[2];
  const float* bq  = (const float*)d_in[3];
  const float* Wk  = (const float*)d_in[4];
  const float* bk  = (const float*)d_in[5];
  const float* Wv  = (const float*)d_in[6];
  const float* bv  = (const float*)d_in[7];
  const float* Wo  = (const float*)d_in[8];
  const float* bo  = (const float*)d_in[9];
  const float* g1  = (const float*)d_in[10];
  const float* b1  = (const float*)d_in[11];
  const float* g2  = (const float*)d_in[12];
  const float* b2  = (const float*)d_in[13];
  const float* W1  = (const float*)d_in[14];
  const float* bf1 = (const float*)d_in[15];
  const float* W2  = (const float*)d_in[16];
  const float* bff2 = (const float*)d_in[17];
  const float* lsc = (const float*)d_in[18];
  const float* alp = (const float*)d_in[19];

  char* ws = (char*)d_ws;
  size_t off = 0;
  auto alloc = [&](size_t bytes) -> char* {
    char* p = ws + off;
    off += (bytes + 255) & ~(size_t)255;
    return p;
  };
  unsigned short* WqT = (unsigned short*)alloc((size_t)65536 * 2);
  unsigned short* WkT = (unsigned short*)alloc((size_t)131072 * 2);  // contiguous
  unsigned short* WvT = (unsigned short*)alloc((size_t)131072 * 2);  // with WkT
  unsigned short* WoT = (unsigned short*)alloc((size_t)65536 * 2);
  unsigned short* W1T = (unsigned short*)alloc((size_t)262144 * 2);
  unsigned short* W2T = (unsigned short*)alloc((size_t)262144 * 2);
  float*          bkv  = (float*)alloc(512 * 4);
  float*          kbuf = (float*)alloc((size_t)BT_ * CV_ * 4);
  float*          vbuf = (float*)alloc((size_t)BT_ * CV_ * 4);
  // Union region U:
  //   xbuf bf16 @U+0       (16.78 MB; o-proj rewrites as y0 in place)
  //   qbuf bf16 @U+16.78MB (16.78 MB; attn rewrites as aligned in place)
  //   hbuf bf16 @U+0       (67.1 MB full / 33.55 MB halved, FFN phase)
  char* U = ws + off;
  unsigned short* xbuf = (unsigned short*)U;
  unsigned short* qbuf = (unsigned short*)(U + 16777216);
  unsigned short* hbuf = (unsigned short*)U;
  float*          ybuf = (float*)d_out;
  bool fullFFN = (ws_size >= off + (size_t)67108864);

  // 1. prep: LN1 + weight convT + kv bias  (8192 + 3586 blocks)
  prep_kernel<<<11778, 256, 0, stream>>>(visual, g1, b1, xbuf,
                                         Wq, Wk, Wv, Wo, W1, W2,
                                         WqT, WkT, WvT, WoT, W1T, W2T,
                                         bk, bv, bkv);
  // 2. q = x @ Wq + bq  (bf16)
  gemm_fast<128><<<dim3(256, 2), 256, 0, stream>>>(
      xbuf, WqT, bq, nullptr, nullptr, qbuf, MROW, 256, 256, 0);
  // 3. k|v = text @ [WkT;WvT]^T + bkv  (fp32 split outputs)
  gemm_kv<<<dim3(10, 8), 256, 0, stream>>>(text, WkT, bkv, kbuf, vbuf);
  // 4. attention (pad + k-norm fused): qbuf -> qbuf in place
  attn_kernel<<<dim3(16, NH_, NB), 256, 0, stream>>>(qbuf, kbuf, vbuf, text, lsc);
  // 5. y0 = x + alpha * (aligned @ Wo + bo) -> xbuf in place
  gemm_fast<128><<<dim3(256, 2), 256, 0, stream>>>(
      qbuf, WoT, bo, xbuf, alp, xbuf, MROW, 256, 256, 0);
  // 6. LN2: y0 (bf16) -> y (fp32, in d_out)
  ln_kernel<<<8192, 256, 0, stream>>>(xbuf, g2, b2, ybuf);
  // 7+8. FFN (single-shot if workspace allows, else two M-halves)
  if (fullFFN) {
    gemm_fast<128><<<dim3(256, 8), 256, 0, stream>>>(
        ybuf, W1T, bf1, nullptr, nullptr, hbuf, MROW, 1024, 256, 2 | 4);
    gemm_fast<64><<<dim3(256, 4), 256, 0, stream>>>(
        hbuf, W2T, bff2, ybuf, nullptr, (void*)ybuf, MROW, 256, 1024, 1 | 8);
  } else {
    for (int half = 0; half < 2; ++half) {
      const float* yh = ybuf + (size_t)half * 16384 * CV_;
      gemm_fast<128><<<dim3(128, 8), 256, 0, stream>>>(
          yh, W1T, bf1, nullptr, nullptr, hbuf, 16384, 1024, 256, 2 | 4);
      gemm_fast<64><<<dim3(128, 4), 256, 0, stream>>>(
          hbuf, W2T, bff2, yh, nullptr, (void*)yh, 16384, 256, 1024, 1 | 8);
    }
  }
}

// Round 6
// 342.582 us; speedup vs baseline: 1.1827x; 1.0602x over previous
//
#include <hip/hip_runtime.h>
#include <math.h>

// Problem constants
#define NB   8
#define NPIX 4096          // H*W
#define MROW 32768         // B*H*W
#define CV_  256
#define TT   77
#define CT_  512
#define NH_  8
#define DH_  32
#define BT_  616           // B*T

typedef __bf16 bf16x8 __attribute__((ext_vector_type(8)));
typedef float  f32x4  __attribute__((ext_vector_type(4)));
typedef float  f32x2  __attribute__((ext_vector_type(2)));

__device__ __forceinline__ float bf2f(unsigned short u) {
  return __uint_as_float(((unsigned)u) << 16);
}
__device__ __forceinline__ unsigned short f2b(float f) {
  unsigned u = __float_as_uint(f);
  return (unsigned short)((u + 0x7FFFu + ((u >> 16) & 1u)) >> 16);
}
__device__ __forceinline__ unsigned pack2(float lo, float hi) {
  return ((unsigned)f2b(hi) << 16) | (unsigned)f2b(lo);
}
__device__ __forceinline__ void async_copy16(const unsigned short* g,
                                             unsigned short* l) {
  __builtin_amdgcn_global_load_lds(
      (const __attribute__((address_space(1))) void*)g,
      (__attribute__((address_space(3))) void*)l, 16, 0, 0);
}

// ---- prep: LN1 (blocks 0..8191) + weight convT + kv bias (blocks 8192+) ----
__global__ __launch_bounds__(256) void prep_kernel(
    const float* __restrict__ visual, const float* __restrict__ g1,
    const float* __restrict__ b1, unsigned short* __restrict__ xbuf,
    const float* __restrict__ s0, const float* __restrict__ s1,
    const float* __restrict__ s2, const float* __restrict__ s3,
    const float* __restrict__ s4, const float* __restrict__ s5,
    unsigned short* __restrict__ d0, unsigned short* __restrict__ d1,
    unsigned short* __restrict__ d2, unsigned short* __restrict__ d3,
    unsigned short* __restrict__ d4, unsigned short* __restrict__ d5,
    const float* __restrict__ bk, const float* __restrict__ bv,
    float* __restrict__ bkv) {
  int bx = blockIdx.x;
  if (bx < 8192) {                       // LN1: visual fp32 -> x bf16
    int wave = threadIdx.x >> 6, lane = threadIdx.x & 63;
    int row = bx * 4 + wave;
    size_t base = (size_t)row * 256 + lane * 4;
    float4 f = *reinterpret_cast<const float4*>(visual + base);
    float v0 = f.x, v1 = f.y, v2 = f.z, v3 = f.w;
    float s = v0 + v1 + v2 + v3;
    float q = v0 * v0 + v1 * v1 + v2 * v2 + v3 * v3;
#pragma unroll
    for (int off = 1; off < 64; off <<= 1) {
      s += __shfl_xor(s, off);
      q += __shfl_xor(q, off);
    }
    float mean = s * (1.0f / 256.0f);
    float var  = q * (1.0f / 256.0f) - mean * mean;
    float rstd = rsqrtf(var + 1e-5f);
    float4 gv = *reinterpret_cast<const float4*>(g1 + lane * 4);
    float4 bv4 = *reinterpret_cast<const float4*>(b1 + lane * 4);
    ushort4 o;
    o.x = f2b((v0 - mean) * rstd * gv.x + bv4.x);
    o.y = f2b((v1 - mean) * rstd * gv.y + bv4.y);
    o.z = f2b((v2 - mean) * rstd * gv.z + bv4.z);
    o.w = f2b((v3 - mean) * rstd * gv.w + bv4.w);
    *reinterpret_cast<ushort4*>(xbuf + base) = o;
    return;
  }
  int gi = (bx - 8192) * 256 + threadIdx.x;
  const float* src; unsigned short* dst; int R, C, idx;
  if      (gi < 65536)  { src=s0; dst=d0; R=256;  C=256;  idx=gi; }
  else if (gi < 196608) { src=s1; dst=d1; R=512;  C=256;  idx=gi-65536; }
  else if (gi < 327680) { src=s2; dst=d2; R=512;  C=256;  idx=gi-196608; }
  else if (gi < 393216) { src=s3; dst=d3; R=256;  C=256;  idx=gi-327680; }
  else if (gi < 655360) { src=s4; dst=d4; R=256;  C=1024; idx=gi-393216; }
  else if (gi < 917504) { src=s5; dst=d5; R=1024; C=256;  idx=gi-655360; }
  else if (gi < 918016) {
    int i = gi - 917504;
    bkv[i] = (i < 256) ? bk[i] : bv[i - 256];
    return;
  } else return;
  int r = idx / C, c = idx - r * C;
  dst[(size_t)c * R + r] = f2b(src[idx]);
}

// ------------- fast MFMA GEMM (m97 structure): C[M,N] = A @ Bt^T ---------
// BM=128, BK=32, BN template (64/128). 256 thr / 4 waves. A bf16 (async).
// flags: bit0 out fp32, bit1 exact-GELU, bit3 resid fp32
template <int BN>
__global__ __launch_bounds__(256) void gemm_fast(
    const unsigned short* __restrict__ A, const unsigned short* __restrict__ Bt,
    const float* __restrict__ bias, const void* resid,
    const float* __restrict__ alpha_ptr, void* out,
    int M, int N, int K, int flags) {
  constexpr int NI  = BN / 32;
  constexpr int CHB = BN / 16;
  __shared__ unsigned short lA[128 * 32];
  __shared__ unsigned short lB[BN * 32];
  int tid = threadIdx.x;
  int bm = blockIdx.x * 128, bn = blockIdx.y * BN;
  int lane = tid & 63, wave = tid >> 6;
  int wm = (wave & 1) * 64, wn = (wave >> 1) * (BN / 2);
  int l15 = lane & 15, quad = lane >> 4;
  int crow = lane >> 2, ccol = (lane & 3) * 8;
  f32x4 acc[4][NI] = {};
  for (int k0 = 0; k0 < K; k0 += 32) {
#pragma unroll
    for (int ch = 0; ch < 2; ++ch) {
      int c = wave * 2 + ch;
      async_copy16(A + (size_t)(bm + c * 16 + crow) * K + k0 + ccol,
                   &lA[c * 512]);
    }
#pragma unroll
    for (int ch = wave; ch < CHB; ch += 4)
      async_copy16(Bt + (size_t)(bn + ch * 16 + crow) * K + k0 + ccol,
                   &lB[ch * 512]);
    __syncthreads();
    bf16x8 af[4], bfr[NI];
#pragma unroll
    for (int mi = 0; mi < 4; ++mi)
      af[mi] = *reinterpret_cast<const bf16x8*>(&lA[(wm + mi * 16 + l15) * 32 + quad * 8]);
#pragma unroll
    for (int ni = 0; ni < NI; ++ni)
      bfr[ni] = *reinterpret_cast<const bf16x8*>(&lB[(wn + ni * 16 + l15) * 32 + quad * 8]);
#pragma unroll
    for (int mi = 0; mi < 4; ++mi)
#pragma unroll
      for (int ni = 0; ni < NI; ++ni)
        acc[mi][ni] = __builtin_amdgcn_mfma_f32_16x16x32_bf16(af[mi], bfr[ni],
                                                              acc[mi][ni], 0, 0, 0);
    __syncthreads();
  }
  float alpha = alpha_ptr ? *alpha_ptr : 1.0f;
#pragma unroll
  for (int mi = 0; mi < 4; ++mi) {
#pragma unroll
    for (int ni = 0; ni < NI; ++ni) {
      int gcol = bn + wn + ni * 16 + l15;
      float bsf = bias ? bias[gcol] : 0.0f;
#pragma unroll
      for (int r = 0; r < 4; ++r) {
        int grow = bm + wm + mi * 16 + quad * 4 + r;
        float v = acc[mi][ni][r] + bsf;
        if (flags & 2) v = 0.5f * v * (1.0f + erff(v * 0.70710678118654752f));
        size_t oi = (size_t)grow * N + gcol;
        if (resid) {
          float rv = (flags & 8) ? ((const float*)resid)[oi]
                                 : bf2f(((const unsigned short*)resid)[oi]);
          v = rv + alpha * v;
        }
        if (flags & 1) ((float*)out)[oi] = v;
        else           ((unsigned short*)out)[oi] = f2b(v);
      }
    }
  }
}

// ---- fused o-proj + residual + LN2: per 128-row block owns full rows ----
// y0 = x + alpha*(aligned @ WoT^T + bo); y = LN(y0)*g2+b2
// writes y bf16 -> ybf (in-place over x rows) and y fp32 -> yf32 (d_out)
__global__ __launch_bounds__(256) void gemm_oln(
    const unsigned short* __restrict__ A, const unsigned short* __restrict__ Bt,
    const float* __restrict__ bias, const unsigned short* __restrict__ xres,
    const float* __restrict__ alpha_ptr,
    const float* __restrict__ g2, const float* __restrict__ b2,
    unsigned short* __restrict__ ybf, float* __restrict__ yf32) {
  __shared__ unsigned short sm[32768];       // 64 KB union
  unsigned short* lA = sm;                   // 128*32
  unsigned short* lB = sm + 4096;            // 256*32
  unsigned short* yt = sm;                   // 128*256 (phase 2)
  const int K = 256;
  int tid = threadIdx.x;
  int bm = blockIdx.x * 128;
  int lane = tid & 63, wave = tid >> 6;
  int wm = (wave & 1) * 64, wn = (wave >> 1) * 128;
  int l15 = lane & 15, quad = lane >> 4;
  int crow = lane >> 2, ccol = (lane & 3) * 8;
  f32x4 acc[4][8] = {};
  for (int k0 = 0; k0 < K; k0 += 32) {
#pragma unroll
    for (int ch = 0; ch < 2; ++ch) {
      int c = wave * 2 + ch;
      async_copy16(A + (size_t)(bm + c * 16 + crow) * K + k0 + ccol,
                   &lA[c * 512]);
    }
#pragma unroll
    for (int ch = wave; ch < 16; ch += 4)
      async_copy16(Bt + (size_t)(ch * 16 + crow) * K + k0 + ccol,
                   &lB[ch * 512]);
    __syncthreads();
    bf16x8 af[4], bfr[8];
#pragma unroll
    for (int mi = 0; mi < 4; ++mi)
      af[mi] = *reinterpret_cast<const bf16x8*>(&lA[(wm + mi * 16 + l15) * 32 + quad * 8]);
#pragma unroll
    for (int ni = 0; ni < 8; ++ni)
      bfr[ni] = *reinterpret_cast<const bf16x8*>(&lB[(wn + ni * 16 + l15) * 32 + quad * 8]);
#pragma unroll
    for (int mi = 0; mi < 4; ++mi)
#pragma unroll
      for (int ni = 0; ni < 8; ++ni)
        acc[mi][ni] = __builtin_amdgcn_mfma_f32_16x16x32_bf16(af[mi], bfr[ni],
                                                              acc[mi][ni], 0, 0, 0);
    __syncthreads();
  }
  float alpha = *alpha_ptr;
  // phase 1: y0 (bf16) into LDS tile
#pragma unroll
  for (int mi = 0; mi < 4; ++mi) {
#pragma unroll
    for (int ni = 0; ni < 8; ++ni) {
      int gcol = wn + ni * 16 + l15;
      float bsf = bias[gcol];
#pragma unroll
      for (int r = 0; r < 4; ++r) {
        int lrow = wm + mi * 16 + quad * 4 + r;
        float v = acc[mi][ni][r] + bsf;
        float y0 = bf2f(xres[(size_t)(bm + lrow) * 256 + gcol]) + alpha * v;
        yt[lrow * 256 + gcol] = f2b(y0);
      }
    }
  }
  __syncthreads();
  // phase 2: LN per row (wave handles rows wave*32..+31; lane owns 4 cols)
  for (int it = 0; it < 32; ++it) {
    int row = wave * 32 + it;
    ushort4 u = *reinterpret_cast<const ushort4*>(&yt[row * 256 + lane * 4]);
    float v0 = bf2f(u.x), v1 = bf2f(u.y), v2 = bf2f(u.z), v3 = bf2f(u.w);
    float s = v0 + v1 + v2 + v3;
    float q = v0 * v0 + v1 * v1 + v2 * v2 + v3 * v3;
#pragma unroll
    for (int off = 1; off < 64; off <<= 1) {
      s += __shfl_xor(s, off);
      q += __shfl_xor(q, off);
    }
    float mean = s * (1.0f / 256.0f);
    float var  = q * (1.0f / 256.0f) - mean * mean;
    float rstd = rsqrtf(var + 1e-5f);
    float4 gv = *reinterpret_cast<const float4*>(g2 + lane * 4);
    float4 bv = *reinterpret_cast<const float4*>(b2 + lane * 4);
    float o0 = (v0 - mean) * rstd * gv.x + bv.x;
    float o1 = (v1 - mean) * rstd * gv.y + bv.y;
    float o2 = (v2 - mean) * rstd * gv.z + bv.z;
    float o3 = (v3 - mean) * rstd * gv.w + bv.w;
    size_t base = (size_t)(bm + row) * 256 + lane * 4;
    ushort4 ob;
    ob.x = f2b(o0); ob.y = f2b(o1); ob.z = f2b(o2); ob.w = f2b(o3);
    *reinterpret_cast<ushort4*>(ybf + base) = ob;
    *reinterpret_cast<float4*>(yf32 + base) = make_float4(o0, o1, o2, o3);
  }
}

// ------ kv GEMM: [k|v](616,512) = text @ [WkT;WvT]^T, split fp32 outputs --
__global__ __launch_bounds__(256) void gemm_kv(
    const float* __restrict__ A, const unsigned short* __restrict__ Bt,
    const float* __restrict__ bias, float* __restrict__ kout,
    float* __restrict__ vout) {
  __shared__ unsigned short lA[64 * 40];
  __shared__ unsigned short lB[64 * 40];
  const int M = BT_, K = CT_;
  int tid = threadIdx.x;
  int bm = blockIdx.x * 64, bn = blockIdx.y * 64;
  int srow = tid >> 2, sc8 = (tid & 3) * 8;
  int lane = tid & 63, wave = tid >> 6;
  int wm = (wave & 1) * 32, wn = (wave >> 1) * 32;
  int l15 = lane & 15, quad = lane >> 4;
  f32x4 acc[2][2] = {};
  int gm = bm + srow, gn = bn + srow;
  const bool aok = (gm < M);
  for (int k0 = 0; k0 < K; k0 += 32) {
    uint4 apk = make_uint4(0, 0, 0, 0);
    if (aok) {
      const float* Af = A + (size_t)gm * K + k0 + sc8;
      float4 f0 = *reinterpret_cast<const float4*>(Af);
      float4 f1 = *reinterpret_cast<const float4*>(Af + 4);
      apk.x = pack2(f0.x, f0.y); apk.y = pack2(f0.z, f0.w);
      apk.z = pack2(f1.x, f1.y); apk.w = pack2(f1.z, f1.w);
    }
    uint4 bpk = *reinterpret_cast<const uint4*>(Bt + (size_t)gn * K + k0 + sc8);
    *reinterpret_cast<uint4*>(&lA[srow * 40 + sc8]) = apk;
    *reinterpret_cast<uint4*>(&lB[srow * 40 + sc8]) = bpk;
    __syncthreads();
    bf16x8 a0 = *reinterpret_cast<const bf16x8*>(&lA[(wm + l15) * 40 + quad * 8]);
    bf16x8 a1 = *reinterpret_cast<const bf16x8*>(&lA[(wm + 16 + l15) * 40 + quad * 8]);
    bf16x8 b0 = *reinterpret_cast<const bf16x8*>(&lB[(wn + l15) * 40 + quad * 8]);
    bf16x8 b1 = *reinterpret_cast<const bf16x8*>(&lB[(wn + 16 + l15) * 40 + quad * 8]);
    acc[0][0] = __builtin_amdgcn_mfma_f32_16x16x32_bf16(a0, b0, acc[0][0], 0, 0, 0);
    acc[0][1] = __builtin_amdgcn_mfma_f32_16x16x32_bf16(a0, b1, acc[0][1], 0, 0, 0);
    acc[1][0] = __builtin_amdgcn_mfma_f32_16x16x32_bf16(a1, b0, acc[1][0], 0, 0, 0);
    acc[1][1] = __builtin_amdgcn_mfma_f32_16x16x32_bf16(a1, b1, acc[1][1], 0, 0, 0);
    __syncthreads();
  }
#pragma unroll
  for (int mt = 0; mt < 2; ++mt) {
#pragma unroll
    for (int nt = 0; nt < 2; ++nt) {
      int gcol = bn + wn + nt * 16 + l15;
      float bsf = bias[gcol];
#pragma unroll
      for (int r = 0; r < 4; ++r) {
        int grow = bm + wm + mt * 16 + quad * 4 + r;
        if (grow >= M) continue;
        float v = acc[mt][nt][r] + bsf;
        if (gcol < 256) kout[(size_t)grow * 256 + gcol] = v;
        else            vout[(size_t)grow * 256 + gcol - 256] = v;
      }
    }
  }
}

// ---------------- attention: pad + k-norm + top-5 cosine attention -------
#define KSTR 36
#define VSTR 33
__global__ __launch_bounds__(256) void attn_kernel(
    unsigned short* qa, const float* __restrict__ k,
    const float* __restrict__ v, const float* __restrict__ text,
    const float* __restrict__ ls_ptr) {
  __shared__ float ks[TT * KSTR];
  __shared__ float vs[TT * VSTR];
  __shared__ float ps[TT];
  __shared__ int allpad_s;
  int tid = threadIdx.x;
  int h = blockIdx.y, b = blockIdx.z;
  size_t kvbase = (size_t)b * TT * CV_ + h * DH_;
  for (int idx = tid; idx < TT * DH_; idx += 256) {
    int t = idx >> 5, d = idx & 31;
    ks[t * KSTR + d] = k[kvbase + (size_t)t * CV_ + d];
    vs[t * VSTR + d] = v[kvbase + (size_t)t * CV_ + d];
  }
  if (tid == 0) allpad_s = 1;
  if (tid < TT) {
    const float4* tp = reinterpret_cast<const float4*>(
        text + ((size_t)b * TT + tid) * CT_);
    float s = 0.f;
    for (int i = 0; i < 128; ++i) {
      float4 f = tp[i];
      s += fabsf(f.x) + fabsf(f.y) + fabsf(f.z) + fabsf(f.w);
    }
    ps[tid] = (s <= 1e-6f) ? 1.0f : 0.0f;
  }
  __syncthreads();
  if (tid < TT) {
    float ssum = 0.f;
#pragma unroll
    for (int d = 0; d < 32; ++d) { float x = ks[tid * KSTR + d]; ssum += x * x; }
    float sc = 1.0f / fmaxf(sqrtf(ssum), 1e-6f);
#pragma unroll
    for (int d = 0; d < 32; ++d) ks[tid * KSTR + d] *= sc;
    if (ps[tid] == 0.0f) allpad_s = 0;
  }
  __syncthreads();
  int allpad = allpad_s;

  int n = blockIdx.x * 256 + tid;
  unsigned short* qp = qa + ((size_t)b * NPIX + n) * CV_ + h * DH_;
  float qv[32];
#pragma unroll
  for (int i = 0; i < 8; ++i) {
    ushort4 u = reinterpret_cast<const ushort4*>(qp)[i];
    qv[4 * i] = bf2f(u.x); qv[4 * i + 1] = bf2f(u.y);
    qv[4 * i + 2] = bf2f(u.z); qv[4 * i + 3] = bf2f(u.w);
  }
  float ss = 0.f;
#pragma unroll
  for (int d = 0; d < 32; ++d) ss += qv[d] * qv[d];
  float ls = *ls_ptr;
  ls = fminf(fmaxf(ls, -2.0f), 2.0f);
  float scale = expf(ls) * 0.17677669529663687f;
  float rn = scale / fmaxf(sqrtf(ss), 1e-6f);
  f32x2 qv2[16];
#pragma unroll
  for (int j = 0; j < 16; ++j) {
    qv2[j][0] = qv[2 * j] * rn;
    qv2[j][1] = qv[2 * j + 1] * rn;
  }

  float tv0 = -INFINITY, tv1 = -INFINITY, tv2 = -INFINITY, tv3 = -INFINITY, tv4 = -INFINITY;
  int   ti0 = 0, ti1 = 0, ti2 = 0, ti3 = 0, ti4 = 0;
  for (int t = 0; t < TT; ++t) {
    if (ps[t] != 0.0f) continue;
    const f32x2* kp = reinterpret_cast<const f32x2*>(&ks[t * KSTR]);
    f32x2 a2 = {0.f, 0.f};
#pragma unroll
    for (int j = 0; j < 16; ++j) a2 += qv2[j] * kp[j];
    float sdot = a2[0] + a2[1];
    bool g0 = sdot > tv0, g1 = sdot > tv1, g2 = sdot > tv2,
         g3 = sdot > tv3, g4 = sdot > tv4;
    tv4 = g4 ? (g3 ? tv3 : sdot) : tv4;  ti4 = g4 ? (g3 ? ti3 : t) : ti4;
    tv3 = g3 ? (g2 ? tv2 : sdot) : tv3;  ti3 = g3 ? (g2 ? ti2 : t) : ti3;
    tv2 = g2 ? (g1 ? tv1 : sdot) : tv2;  ti2 = g2 ? (g1 ? ti1 : t) : ti2;
    tv1 = g1 ? (g0 ? tv0 : sdot) : tv1;  ti1 = g1 ? (g0 ? ti0 : t) : ti1;
    tv0 = g0 ? sdot : tv0;               ti0 = g0 ? t : ti0;
  }
  float o[32];
#pragma unroll
  for (int d = 0; d < 32; ++d) o[d] = 0.f;
  if (!allpad && tv0 > -INFINITY) {
    float e0 = 1.0f;
    float e1 = expf(tv1 - tv0);
    float e2 = expf(tv2 - tv0);
    float e3 = expf(tv3 - tv0);
    float e4 = expf(tv4 - tv0);
    float inv = 1.0f / (e0 + e1 + e2 + e3 + e4);
    const float* v0p = &vs[ti0 * VSTR]; const float* v1p = &vs[ti1 * VSTR];
    const float* v2p = &vs[ti2 * VSTR]; const float* v3p = &vs[ti3 * VSTR];
    const float* v4p = &vs[ti4 * VSTR];
#pragma unroll
    for (int d = 0; d < 32; ++d)
      o[d] = (e0 * v0p[d] + e1 * v1p[d] + e2 * v2p[d] + e3 * v3p[d] + e4 * v4p[d]) * inv;
  }
#pragma unroll
  for (int i = 0; i < 8; ++i) {
    ushort4 u;
    u.x = f2b(o[4 * i]);     u.y = f2b(o[4 * i + 1]);
    u.z = f2b(o[4 * i + 2]); u.w = f2b(o[4 * i + 3]);
    reinterpret_cast<ushort4*>(qp)[i] = u;
  }
}

extern "C" void kernel_launch(void* const* d_in, const int* in_sizes, int n_in,
                              void* d_out, int out_size, void* d_ws, size_t ws_size,
                              hipStream_t stream) {
  const float* visual = (const float*)d_in[0];
  const float* text   = (const float*)d_in[1];
  const float* Wq  = (const float*)d_in[2];
  const float* bq  = (const float*)d_in[3];
  const float* Wk  = (const float*)d_in[4];
  const float* bk  = (const float*)d_in[5];
  const float* Wv  = (const float*)d_in[6];
  const float* bv  = (const float*)d_in[7];
  const float* Wo  = (const float*)d_in[8];
  const float* bo  = (const float*)d_in[9];
  const float* g1  = (const float*)d_in[10];
  const float* b1  = (const float*)d_in[11];
  const float* g2  = (const float*)d_in[12];
  const float* b2  = (const float*)d_in[13];
  const float* W1  = (const float*)d_in[14];
  const float* bf1 = (const float*)d_in[15];
  const float* W2  = (const float*)d_in[16];
  const float* bff2 = (const float*)d_in[17];
  const float* lsc = (const float*)d_in[18];
  const float* alp = (const float*)d_in[19];

  char* ws = (char*)d_ws;
  size_t off = 0;
  auto alloc = [&](size_t bytes) -> char* {
    char* p = ws + off;
    off += (bytes + 255) & ~(size_t)255;
    return p;
  };
  unsigned short* WqT = (unsigned short*)alloc((size_t)65536 * 2);
  unsigned short* WkT = (unsigned short*)alloc((size_t)131072 * 2);  // contiguous
  unsigned short* WvT = (unsigned short*)alloc((size_t)131072 * 2);  // with WkT
  unsigned short* WoT = (unsigned short*)alloc((size_t)65536 * 2);
  unsigned short* W1T = (unsigned short*)alloc((size_t)262144 * 2);
  unsigned short* W2T = (unsigned short*)alloc((size_t)262144 * 2);
  float*          bkv  = (float*)alloc(512 * 4);
  float*          kbuf = (float*)alloc((size_t)BT_ * CV_ * 4);
  float*          vbuf = (float*)alloc((size_t)BT_ * CV_ * 4);
  // Union region U:
  //   xbuf bf16 @U+0       (x; gemm_oln rewrites as y bf16, rows block-owned)
  //   qbuf bf16 @U+16.78MB (q; attn rewrites as aligned in place)
  //   hbuf bf16 @U+16.78MB (67.1 MB full / 33.55 MB halved; qbuf dead by then,
  //                         xbuf holds y = FFN1's A, must NOT overlap)
  char* U = ws + off;
  unsigned short* xbuf = (unsigned short*)U;
  unsigned short* qbuf = (unsigned short*)(U + 16777216);
  unsigned short* hbuf = (unsigned short*)(U + 16777216);
  float*          ybuf = (float*)d_out;
  bool fullFFN = (ws_size >= off + (size_t)16777216 + (size_t)67108864);

  // 1. prep: LN1 + weight convT + kv bias
  prep_kernel<<<11778, 256, 0, stream>>>(visual, g1, b1, xbuf,
                                         Wq, Wk, Wv, Wo, W1, W2,
                                         WqT, WkT, WvT, WoT, W1T, W2T,
                                         bk, bv, bkv);
  // 2. q = x @ Wq + bq  (bf16)
  gemm_fast<128><<<dim3(256, 2), 256, 0, stream>>>(
      xbuf, WqT, bq, nullptr, nullptr, qbuf, MROW, 256, 256, 0);
  // 3. k|v = text @ [WkT;WvT]^T + bkv  (fp32 split outputs)
  gemm_kv<<<dim3(10, 8), 256, 0, stream>>>(text, WkT, bkv, kbuf, vbuf);
  // 4. attention (pad + k-norm fused): qbuf -> qbuf in place
  attn_kernel<<<dim3(16, NH_, NB), 256, 0, stream>>>(qbuf, kbuf, vbuf, text, lsc);
  // 5. fused o-proj + residual + LN2: writes y bf16 (xbuf) + y fp32 (d_out)
  gemm_oln<<<256, 256, 0, stream>>>(qbuf, WoT, bo, xbuf, alp, g2, b2,
                                    xbuf, ybuf);
  // 6+7. FFN (single-shot if workspace allows, else two M-halves)
  if (fullFFN) {
    gemm_fast<128><<<dim3(256, 8), 256, 0, stream>>>(
        xbuf, W1T, bf1, nullptr, nullptr, hbuf, MROW, 1024, 256, 2);
    gemm_fast<64><<<dim3(256, 4), 256, 0, stream>>>(
        hbuf, W2T, bff2, ybuf, nullptr, (void*)ybuf, MROW, 256, 1024, 1 | 8);
  } else {
    for (int half = 0; half < 2; ++half) {
      const unsigned short* xh = xbuf + (size_t)half * 16384 * CV_;
      const float* yh = ybuf + (size_t)half * 16384 * CV_;
      gemm_fast<128><<<dim3(128, 8), 256, 0, stream>>>(
          xh, W1T, bf1, nullptr, nullptr, hbuf, 16384, 1024, 256, 2);
      gemm_fast<64><<<dim3(128, 4), 256, 0, stream>>>(
          hbuf, W2T, bff2, yh, nullptr, (void*)yh, 16384, 256, 1024, 1 | 8);
    }
  }
}